// Round 6
// baseline (424.157 us; speedup 1.0000x reference)
//
#include <hip/hip_runtime.h>
#include <cstdint>
#include <cstddef>

// ---------------------------------------------------------------------------
// GAttn round 5: 2-phase double-buffered K-loops (guide T3 minimum recipe) in
// t2/t3/t4 — STAGE(next) issued before compute(cur), one barrier/iter, load
// latency hidden under ds_read+MFMA. t6 unchanged (LDS 64KB/WG limit).
// Rest identical to round 4 (passed 410 µs, absmax 2.4e-4).
// ---------------------------------------------------------------------------

#define DI __device__ __forceinline__

typedef __attribute__((ext_vector_type(8))) short bf16x8;
typedef __attribute__((ext_vector_type(4))) short bf16x4;
typedef __attribute__((ext_vector_type(4))) float f32x4;

static constexpr int Cc = 256;
static constexpr int NN = 16384;

DI float bf2f(short s){ unsigned int u = ((unsigned int)(unsigned short)s) << 16; float f; __builtin_memcpy(&f, &u, 4); return f; }
DI short f2bf(float f){ unsigned int u; __builtin_memcpy(&u, &f, 4); u += 0x7fffu + ((u >> 16) & 1u); return (short)(u >> 16); }

typedef __attribute__((address_space(1))) const unsigned int gu32;
typedef __attribute__((address_space(3))) unsigned int lu32;
DI void gload16(const short* g, short* l){
    __builtin_amdgcn_global_load_lds((gu32*)g, (lu32*)l, 16, 0, 0);
}

// gelu(x) = 0.5x(1+erf(x/sqrt2)); erf via A&S 7.1.26, |abs err| < 1.5e-7
DI float geluf(float x){
    float zz = x * 0.70710678118654752f;
    float az = fabsf(zz);
    float t  = __builtin_amdgcn_rcpf(fmaf(0.3275911f, az, 1.0f));
    float p  = fmaf(fmaf(fmaf(fmaf(1.061405429f, t, -1.453152027f), t,
                   1.421413741f), t, -0.284496736f), t, 0.254829592f) * t;
    float e  = __expf(-az * az);
    float er = copysignf(1.0f - p * e, zz);
    return 0.5f * x * (1.0f + er);
}
// softplus(x) = max(x,0) + log(1+exp(-|x|)); log arg in (1,2] -> v_log accurate
DI float softplusf(float x){
    float e = __expf(-fabsf(x));
    return fmaxf(x, 0.0f) + __logf(1.0f + e);
}

// ---------------- TW: one-shot weight fp32->bf16 ----------------
__global__ __launch_bounds__(256) void tw_conv(
    const float* __restrict__ W0, const float* __restrict__ W1,
    const float* __restrict__ W2, const float* __restrict__ W3,
    const float* __restrict__ W4, const float* __restrict__ W5,
    const float* __restrict__ W6, short* __restrict__ dst)
{
    const float* srcs[7] = {W0, W1, W2, W3, W4, W5, W6};
    const float* W = srcs[blockIdx.y];
    short* d = dst + (size_t)blockIdx.y * 65536;
    int i = blockIdx.x * 256 + threadIdx.x;
    float4 v = *(const float4*)(W + (size_t)i * 4);
    bf16x4 pk = { f2bf(v.x), f2bf(v.y), f2bf(v.z), f2bf(v.w) };
    *(bf16x4*)(d + (size_t)i * 4) = pk;
}

// ---------------- T0: instance-norm stats ----------------
__global__ __launch_bounds__(256) void t0_stats(const float* __restrict__ x,
                                                float* __restrict__ mu, float* __restrict__ rstd)
{
    int row = blockIdx.x;
    const float4* p = (const float4*)(x + (size_t)row * NN);
    float s = 0.f, ss = 0.f;
    for (int i = threadIdx.x; i < NN/4; i += 256){
        float4 v = p[i];
        s  += v.x + v.y + v.z + v.w;
        ss += v.x*v.x + v.y*v.y + v.z*v.z + v.w*v.w;
    }
    #pragma unroll
    for (int o = 32; o; o >>= 1){ s += __shfl_down(s, o); ss += __shfl_down(ss, o); }
    __shared__ float a0[4], a1[4];
    int w = threadIdx.x >> 6;
    if ((threadIdx.x & 63) == 0){ a0[w] = s; a1[w] = ss; }
    __syncthreads();
    if (threadIdx.x == 0){
        float S = a0[0]+a0[1]+a0[2]+a0[3], SS = a1[0]+a1[1]+a1[2]+a1[3];
        float m = S * (1.f/NN);
        float var = SS * (1.f/NN) - m*m;
        mu[row] = m;
        rstd[row] = rsqrtf(var + 1e-5f);
    }
}

// ---------------- T1: normalize + transpose -> xnT[b][n][c] ----------------
__global__ __launch_bounds__(256) void t1_xnT(const float* __restrict__ x,
                                              const float* __restrict__ mu, const float* __restrict__ rstd,
                                              short* __restrict__ xnT)
{
    int n0 = blockIdx.x * 64, c0 = blockIdx.y * 64, b = blockIdx.z;
    __shared__ __align__(16) short lds[64*72];
    int t = threadIdx.x;
    #pragma unroll
    for (int i = 0; i < 4; i++){
        int idx = i*256 + t;
        int c  = idx >> 4;
        int n4 = idx & 15;
        int cg = b*Cc + c0 + c;
        float4 v = *(const float4*)(x + (size_t)cg*NN + n0 + n4*4);
        float m = mu[cg], rs = rstd[cg];
        int key = (c ^ (c >> 3)) & 7;
        int blk = (n4 >> 1) ^ key;
        bf16x4 pk = { f2bf((v.x-m)*rs), f2bf((v.y-m)*rs), f2bf((v.z-m)*rs), f2bf((v.w-m)*rs) };
        *(bf16x4*)(&lds[c*72 + blk*8 + (n4&1)*4]) = pk;
    }
    __syncthreads();
    #pragma unroll
    for (int i = 0; i < 2; i++){
        int idx = i*256 + t;
        int n  = idx >> 3;
        int c8 = idx & 7;
        bf16x8 pk;
        #pragma unroll
        for (int j = 0; j < 8; j++){
            int c = c8*8 + j;
            int key = (c ^ (c >> 3)) & 7;
            pk[j] = lds[c*72 + (((n >> 3) ^ key))*8 + (n & 7)];
        }
        *(bf16x8*)(xnT + ((size_t)(b*NN + n0 + n))*Cc + c0 + c8*8) = pk;
    }
}

// ---------------- T2: conv1 (4 branches, gelu), 2-phase ----------------
__global__ __launch_bounds__(256) void t2_conv1(const short* __restrict__ xnT,
    const short* __restrict__ wbf,
    const float* __restrict__ bq1, const float* __restrict__ bk1,
    const float* __restrict__ bv,  const float* __restrict__ bg,
    short* __restrict__ y1qk, short* __restrict__ yvg)
{
    int n0 = blockIdx.x * 128;
    int stile = blockIdx.y;             // 0..7
    int b = blockIdx.z;
    int branch = stile >> 1;            // 0=Wq1 1=Wk1 2=Wv 3=Wg
    const short* wb = wbf + (size_t)branch * 65536;
    const float* bs = branch==0 ? bq1 : branch==1 ? bk1 : branch==2 ? bv : bg;
    int s0b = (stile & 1) * 128;
    short* dst; int dcol;
    if (stile < 4){ dst = y1qk; dcol = stile*128; } else { dst = yvg; dcol = (stile-4)*128; }

    __shared__ __align__(16) short Al[2][128*32];
    __shared__ __align__(16) short Bl[2][128*32];
    int t = threadIdx.x, lane = t & 63, wid = t >> 6;
    int wm = (wid & 1) * 64, wn = (wid >> 1) * 64;
    int l15 = lane & 15, g = lane >> 4;
    int srow = wid*16 + (lane >> 2);        // + i*64
    int scol = (lane & 3) * 8;
    int sdst = wid*512 + lane*8;            // + i*2048

    f32x4 acc[4][4];
    #pragma unroll
    for (int i=0;i<4;i++)
        #pragma unroll
        for (int j=0;j<4;j++){ acc[i][j][0]=0.f; acc[i][j][1]=0.f; acc[i][j][2]=0.f; acc[i][j][3]=0.f; }

    const short* xb = xnT + (size_t)(b*NN + n0) * Cc;

    auto stg = [&](int k0, int ph){
        #pragma unroll
        for (int i = 0; i < 2; i++){
            gload16(xb + (size_t)(i*64 + srow)*Cc + k0 + scol, &Al[ph][i*2048 + sdst]);
            gload16(wb + (size_t)(s0b + i*64 + srow)*Cc + k0 + scol, &Bl[ph][i*2048 + sdst]);
        }
    };
    stg(0, 0);
    __syncthreads();
    int ph = 0;
    for (int k0 = 0; k0 < 256; k0 += 32){
        if (k0 + 32 < 256) stg(k0 + 32, ph ^ 1);
        bf16x8 bfr[4];
        #pragma unroll
        for (int ni = 0; ni < 4; ni++) bfr[ni] = *(const bf16x8*)(&Bl[ph][(wn + ni*16 + l15)*32 + g*8]);
        #pragma unroll
        for (int mi = 0; mi < 4; mi++){
            bf16x8 a = *(const bf16x8*)(&Al[ph][(wm + mi*16 + l15)*32 + g*8]);
            #pragma unroll
            for (int ni = 0; ni < 4; ni++)
                acc[mi][ni] = __builtin_amdgcn_mfma_f32_16x16x32_bf16(a, bfr[ni], acc[mi][ni], 0, 0, 0);
        }
        __syncthreads();
        ph ^= 1;
    }
    short* outb = dst + (size_t)(b*NN + n0) * 512 + dcol;
    #pragma unroll
    for (int mi = 0; mi < 4; mi++)
        #pragma unroll
        for (int ni = 0; ni < 4; ni++){
            int coll = wn + ni*16 + l15;
            float bias = bs[s0b + coll];
            #pragma unroll
            for (int r = 0; r < 4; r++){
                int row = wm + mi*16 + g*4 + r;
                outb[(size_t)row*512 + coll] = f2bf(geluf(acc[mi][ni][r] + bias));
            }
        }
}

// ---------------- T3: conv2 (q,k softplus) + ksum, 2-phase ----------------
__global__ __launch_bounds__(256) void t3_conv2(const short* __restrict__ y1qk,
    const short* __restrict__ wbf,
    const float* __restrict__ bq2, const float* __restrict__ bk2,
    short* __restrict__ qkT, float* __restrict__ ksum)
{
    int n0 = blockIdx.x * 128;
    int stile = blockIdx.y;             // 0..3
    int b = blockIdx.z;
    int branch = stile >> 1;            // 0=q, 1=k
    const short* wb = wbf + (size_t)(4 + branch) * 65536;
    const float* bs = branch ? bk2 : bq2;
    int ksrc = branch * 256;
    int s0b = (stile & 1) * 128;

    __shared__ __align__(16) short Al[2][128*32];
    __shared__ __align__(16) short Bl[2][128*32];
    int t = threadIdx.x, lane = t & 63, wid = t >> 6;
    int wm = (wid & 1) * 64, wn = (wid >> 1) * 64;
    int l15 = lane & 15, g = lane >> 4;
    int srow = wid*16 + (lane >> 2);
    int scol = (lane & 3) * 8;
    int sdst = wid*512 + lane*8;

    f32x4 acc[4][4];
    #pragma unroll
    for (int i=0;i<4;i++)
        #pragma unroll
        for (int j=0;j<4;j++){ acc[i][j][0]=0.f; acc[i][j][1]=0.f; acc[i][j][2]=0.f; acc[i][j][3]=0.f; }

    const short* src = y1qk + (size_t)(b*NN + n0) * 512 + ksrc;

    auto stg = [&](int k0, int ph){
        #pragma unroll
        for (int i = 0; i < 2; i++){
            gload16(src + (size_t)(i*64 + srow)*512 + k0 + scol, &Al[ph][i*2048 + sdst]);
            gload16(wb + (size_t)(s0b + i*64 + srow)*Cc + k0 + scol, &Bl[ph][i*2048 + sdst]);
        }
    };
    stg(0, 0);
    __syncthreads();
    int ph = 0;
    for (int k0 = 0; k0 < 256; k0 += 32){
        if (k0 + 32 < 256) stg(k0 + 32, ph ^ 1);
        bf16x8 bfr[4];
        #pragma unroll
        for (int ni = 0; ni < 4; ni++) bfr[ni] = *(const bf16x8*)(&Bl[ph][(wn + ni*16 + l15)*32 + g*8]);
        #pragma unroll
        for (int mi = 0; mi < 4; mi++){
            bf16x8 a = *(const bf16x8*)(&Al[ph][(wm + mi*16 + l15)*32 + g*8]);
            #pragma unroll
            for (int ni = 0; ni < 4; ni++)
                acc[mi][ni] = __builtin_amdgcn_mfma_f32_16x16x32_bf16(a, bfr[ni], acc[mi][ni], 0, 0, 0);
        }
        __syncthreads();
        ph ^= 1;
    }
    short* outb = qkT + (size_t)(b*NN + n0) * 512 + branch*256 + s0b;
    float csum[4] = {0.f, 0.f, 0.f, 0.f};
    #pragma unroll
    for (int mi = 0; mi < 4; mi++)
        #pragma unroll
        for (int ni = 0; ni < 4; ni++){
            int coll = wn + ni*16 + l15;
            float bias = bs[s0b + coll];
            #pragma unroll
            for (int r = 0; r < 4; r++){
                int row = wm + mi*16 + g*4 + r;
                float val = softplusf(acc[mi][ni][r] + bias);
                outb[(size_t)row*512 + coll] = f2bf(val);
                csum[ni] += val;
            }
        }
    if (branch == 1){
        #pragma unroll
        for (int ni = 0; ni < 4; ni++){
            float v = csum[ni];
            v += __shfl_xor(v, 16);
            v += __shfl_xor(v, 32);
            if (g == 0) atomicAdd(&ksum[b*Cc + s0b + wn + ni*16 + l15], v);
        }
    }
}

// ---------------- T3t: transpose k,v to c-major ----------------
__global__ __launch_bounds__(256) void t3t_transpose(const short* __restrict__ qkT, const short* __restrict__ yvg,
                                                     short* __restrict__ kC, short* __restrict__ vC)
{
    int n0 = blockIdx.x * 64;
    int c0 = blockIdx.y * 64;
    int b  = blockIdx.z >> 1;
    int which = blockIdx.z & 1;
    const short* src; short* dst;
    if (which == 0){ src = qkT + (size_t)(b*NN + n0)*512 + 256 + c0; dst = kC + (size_t)(b*Cc + c0)*NN + n0; }
    else           { src = yvg + (size_t)(b*NN + n0)*512 +   0 + c0; dst = vC + (size_t)(b*Cc + c0)*NN + n0; }
    __shared__ __align__(16) short lds[64*72];
    int t = threadIdx.x;
    #pragma unroll
    for (int i = 0; i < 2; i++){
        int idx = i*256 + t;
        int n = idx >> 3, c8 = idx & 7;
        bf16x8 v = *(const bf16x8*)(src + (size_t)n*512 + c8*8);
        int key = (n ^ (n >> 3)) & 7;
        *(bf16x8*)(&lds[n*72 + (c8 ^ key)*8]) = v;
    }
    __syncthreads();
    #pragma unroll
    for (int i = 0; i < 2; i++){
        int idx = i*256 + t;
        int c = idx >> 3, n8 = idx & 7;
        bf16x8 pk;
        #pragma unroll
        for (int j = 0; j < 8; j++){
            int n = n8*8 + j;
            int key = (n ^ (n >> 3)) & 7;
            pk[j] = lds[n*72 + (((c >> 3) ^ key))*8 + (c & 7)];
        }
        *(bf16x8*)(dst + (size_t)c*NN + n8*8) = pk;
    }
}

// ---------------- T4: kv GEMM (atomic K-split), 2-phase ----------------
__global__ __launch_bounds__(256) void t4_kv(const short* __restrict__ kC, const short* __restrict__ vC,
                                             float* __restrict__ kv)
{
    int m0 = blockIdx.x * 128;          // c
    int d0 = blockIdx.y * 128;          // d
    int b  = blockIdx.z >> 5;
    int nb = (blockIdx.z & 31) * 512;

    __shared__ __align__(16) short Al[2][128*32];
    __shared__ __align__(16) short Bl[2][128*32];
    int t = threadIdx.x, lane = t & 63, wid = t >> 6;
    int wm = (wid & 1) * 64, wn = (wid >> 1) * 64;
    int l15 = lane & 15, g = lane >> 4;
    int srow = wid*16 + (lane >> 2);
    int scol = (lane & 3) * 8;
    int sdst = wid*512 + lane*8;

    f32x4 acc[4][4];
    #pragma unroll
    for (int i=0;i<4;i++)
        #pragma unroll
        for (int j=0;j<4;j++){ acc[i][j][0]=0.f; acc[i][j][1]=0.f; acc[i][j][2]=0.f; acc[i][j][3]=0.f; }

    const short* ka = kC + (size_t)(b*Cc + m0)*NN + nb;
    const short* vb = vC + (size_t)(b*Cc + d0)*NN + nb;

    auto stg = [&](int k0, int ph){
        #pragma unroll
        for (int i = 0; i < 2; i++){
            gload16(ka + (size_t)(i*64 + srow)*NN + k0 + scol, &Al[ph][i*2048 + sdst]);
            gload16(vb + (size_t)(i*64 + srow)*NN + k0 + scol, &Bl[ph][i*2048 + sdst]);
        }
    };
    stg(0, 0);
    __syncthreads();
    int ph = 0;
    for (int k0 = 0; k0 < 512; k0 += 32){
        if (k0 + 32 < 512) stg(k0 + 32, ph ^ 1);
        bf16x8 bfr[4];
        #pragma unroll
        for (int ni = 0; ni < 4; ni++) bfr[ni] = *(const bf16x8*)(&Bl[ph][(wn + ni*16 + l15)*32 + g*8]);
        #pragma unroll
        for (int mi = 0; mi < 4; mi++){
            bf16x8 a = *(const bf16x8*)(&Al[ph][(wm + mi*16 + l15)*32 + g*8]);
            #pragma unroll
            for (int ni = 0; ni < 4; ni++)
                acc[mi][ni] = __builtin_amdgcn_mfma_f32_16x16x32_bf16(a, bfr[ni], acc[mi][ni], 0, 0, 0);
        }
        __syncthreads();
        ph ^= 1;
    }
    #pragma unroll
    for (int mi = 0; mi < 4; mi++)
        #pragma unroll
        for (int ni = 0; ni < 4; ni++){
            int coll = wn + ni*16 + l15;
            #pragma unroll
            for (int r = 0; r < 4; r++){
                int row = wm + mi*16 + g*4 + r;
                atomicAdd(&kv[((size_t)b*Cc + m0 + row)*Cc + d0 + coll], acc[mi][ni][r]);
            }
        }
}

// ---------------- T4c: kvT16[d][c] = bf16(kv[c][d]/16) ----------------
__global__ __launch_bounds__(256) void t4c_kvT(const float* __restrict__ kv, short* __restrict__ kvT16)
{
    int d = blockIdx.x, b = blockIdx.y, c = threadIdx.x;
    float v = kv[((size_t)b*Cc + c)*Cc + d] * 0.0625f;
    kvT16[((size_t)b*Cc + d)*Cc + c] = f2bf(v);
}

// ---------------- T5: z = 1/(q.ksum/16 + N) ----------------
__global__ __launch_bounds__(256) void t5_z(const short* __restrict__ qkT, const float* __restrict__ ksum,
                                            float* __restrict__ z)
{
    int b = blockIdx.y;
    int n0 = blockIdx.x * 32;
    __shared__ float ks[256];
    int t = threadIdx.x;
    ks[t] = ksum[b*Cc + t];
    __syncthreads();
    int row = n0 + (t >> 3), l8 = t & 7;
    const short* q = qkT + (size_t)(b*NN + row)*512;
    float acc = 0.f;
    #pragma unroll
    for (int i = 0; i < 4; i++){
        int c8 = i*8 + l8;
        bf16x8 v = *(const bf16x8*)(q + c8*8);
        #pragma unroll
        for (int j = 0; j < 8; j++) acc += bf2f(v[j]) * ks[c8*8 + j];
    }
    acc += __shfl_down(acc, 4, 8);
    acc += __shfl_down(acc, 2, 8);
    acc += __shfl_down(acc, 1, 8);
    if (l8 == 0) z[b*NN + row] = 1.0f / (acc * 0.0625f + 16384.0f);
}

// ---------------- T6: final fused (q.kvT16, gate, Wo conv) ----------------
__global__ __launch_bounds__(256) void t6_final(const short* __restrict__ qkT, const short* __restrict__ kvT16,
    const short* __restrict__ yvg, const float* __restrict__ z,
    const short* __restrict__ wbf, const float* __restrict__ bo, float* __restrict__ out)
{
    int n0 = blockIdx.x * 64, b = blockIdx.y;
    __shared__ __align__(16) short Aq[64*32];
    __shared__ __align__(16) short Bw[256*32];
    __shared__ __align__(16) short S[64*264];
    int t = threadIdx.x, lane = t & 63, wid = t >> 6;
    int l15 = lane & 15, g = lane >> 4;
    const short* wo_bf = wbf + (size_t)6 * 65536;
    int srow = wid*16 + (lane >> 2);        // + i*64
    int scol = (lane & 3) * 8;
    int sdst = wid*512 + lane*8;            // + i*2048

    f32x4 acc[4][4];
    #pragma unroll
    for (int i=0;i<4;i++)
        #pragma unroll
        for (int j=0;j<4;j++){ acc[i][j][0]=0.f; acc[i][j][1]=0.f; acc[i][j][2]=0.f; acc[i][j][3]=0.f; }

    const short* qb = qkT + (size_t)(b*NN + n0)*512;
    const short* kvb = kvT16 + (size_t)b*Cc*Cc;

    // GEMM-a: t[n][d] = sum_c q[n][c] * kvT16[d][c]
    for (int k0 = 0; k0 < 256; k0 += 32){
        __syncthreads();
        gload16(qb + (size_t)srow*512 + k0 + scol, &Aq[sdst]);   // 64 rows, 1 issue
        #pragma unroll
        for (int i = 0; i < 4; i++)
            gload16(kvb + (size_t)(i*64 + srow)*Cc + k0 + scol, &Bw[i*2048 + sdst]);
        __syncthreads();
        bf16x8 bfr[4];
        #pragma unroll
        for (int ni = 0; ni < 4; ni++) bfr[ni] = *(const bf16x8*)(&Bw[(wid*64 + ni*16 + l15)*32 + g*8]);
        #pragma unroll
        for (int mi = 0; mi < 4; mi++){
            bf16x8 a = *(const bf16x8*)(&Aq[(mi*16 + l15)*32 + g*8]);
            #pragma unroll
            for (int ni = 0; ni < 4; ni++)
                acc[mi][ni] = __builtin_amdgcn_mfma_f32_16x16x32_bf16(a, bfr[ni], acc[mi][ni], 0, 0, 0);
        }
    }
    // epilogue-a: s = (t + v) * z * g  -> S[n][d]
    #pragma unroll
    for (int mi = 0; mi < 4; mi++)
        #pragma unroll
        for (int r = 0; r < 4; r++){
            int nl = mi*16 + g*4 + r;
            float zv = z[b*NN + n0 + nl];
            const short* vrow = yvg + (size_t)(b*NN + n0 + nl)*512;
            #pragma unroll
            for (int ni = 0; ni < 4; ni++){
                int d = wid*64 + ni*16 + l15;
                float vv = bf2f(vrow[d]);
                float gg = bf2f(vrow[256 + d]);
                S[nl*264 + d] = f2bf((acc[mi][ni][r] + vv) * zv * gg);
            }
        }
    __syncthreads();

    // GEMM-b: out[o][n] = sum_d Wo[o][d] * S[n][d] + bo
    f32x4 acc2[4][4];
    #pragma unroll
    for (int i=0;i<4;i++)
        #pragma unroll
        for (int j=0;j<4;j++){ acc2[i][j][0]=0.f; acc2[i][j][1]=0.f; acc2[i][j][2]=0.f; acc2[i][j][3]=0.f; }

    for (int k0 = 0; k0 < 256; k0 += 32){
        __syncthreads();
        #pragma unroll
        for (int i = 0; i < 4; i++)
            gload16(wo_bf + (size_t)(i*64 + srow)*Cc + k0 + scol, &Bw[i*2048 + sdst]);
        __syncthreads();
        bf16x8 sfr[4];
        #pragma unroll
        for (int ni = 0; ni < 4; ni++) sfr[ni] = *(const bf16x8*)(&S[(ni*16 + l15)*264 + k0 + g*8]);
        #pragma unroll
        for (int mi = 0; mi < 4; mi++){
            bf16x8 a = *(const bf16x8*)(&Bw[(wid*64 + mi*16 + l15)*32 + g*8]);
            #pragma unroll
            for (int ni = 0; ni < 4; ni++)
                acc2[mi][ni] = __builtin_amdgcn_mfma_f32_16x16x32_bf16(a, sfr[ni], acc2[mi][ni], 0, 0, 0);
        }
    }
    #pragma unroll
    for (int mi = 0; mi < 4; mi++)
        #pragma unroll
        for (int ni = 0; ni < 4; ni++){
            int n = n0 + ni*16 + l15;
            #pragma unroll
            for (int r = 0; r < 4; r++){
                int o = wid*64 + mi*16 + g*4 + r;
                out[((size_t)b*Cc + o)*NN + n] = acc2[mi][ni][r] + bo[o];
            }
        }
}

// ---------------- host ----------------
extern "C" void kernel_launch(void* const* d_in, const int* in_sizes, int n_in,
                              void* d_out, int out_size, void* d_ws, size_t ws_size,
                              hipStream_t stream)
{
    (void)in_sizes; (void)n_in; (void)out_size; (void)ws_size;
    const float* x   = (const float*)d_in[0];
    const float* Wq1 = (const float*)d_in[1];
    const float* bq1 = (const float*)d_in[2];
    const float* Wq2 = (const float*)d_in[3];
    const float* bq2 = (const float*)d_in[4];
    const float* Wk1 = (const float*)d_in[5];
    const float* bk1 = (const float*)d_in[6];
    const float* Wk2 = (const float*)d_in[7];
    const float* bk2 = (const float*)d_in[8];
    const float* Wv  = (const float*)d_in[9];
    const float* bv  = (const float*)d_in[10];
    const float* Wg  = (const float*)d_in[11];
    const float* bg  = (const float*)d_in[12];
    const float* Wo  = (const float*)d_in[13];
    const float* bo  = (const float*)d_in[14];
    float* out = (float*)d_out;

    char* ws = (char*)d_ws;
    float* mu    = (float*)(ws + 0);                //   4 KB
    float* rstd  = (float*)(ws + 4096);             //   4 KB
    float* z     = (float*)(ws + 8192);             // 256 KB  (ends 270336)
    short* kvT16 = (short*)(ws + 270336);           // 512 KB  (ends 794624)
    short* wbf   = (short*)(ws + 794624);           // 896 KB  bf16 weights (ends 1712128)
    float* ksum  = (float*)(ws + 1712128);          //   4 KB  (memset 0)
    float* kv    = (float*)(ws + 1716224);          //   1 MB  (memset 0, ends 2764800)
    short* xnT   = (short*)(ws + 3145728);          //  32 MB  (ends 36700160)
    short* y1qk  = (short*)(ws + 36700160);         //  64 MB  (ends 103809024)
    short* yvg   = (short*)(ws + 103809024);        //  64 MB  (ends 170917888)
    short* qkT   = (short*)(ws + 170917888);        //  64 MB  (ends 238026752)
    short* kC    = xnT;                             //  32 MB  (xnT dead after T2)
    short* vC    = y1qk;                            //  32 MB  (y1qk dead after T3)

    hipMemsetAsync(ws + 1712128, 0, 4096 + 1048576, stream);   // ksum + kv

    tw_conv      <<<dim3(64, 7),      256, 0, stream>>>(Wq1, Wk1, Wv, Wg, Wq2, Wk2, Wo, wbf);
    t0_stats     <<<dim3(1024),       256, 0, stream>>>(x, mu, rstd);
    t1_xnT       <<<dim3(256, 4, 4),  256, 0, stream>>>(x, mu, rstd, xnT);
    t2_conv1     <<<dim3(128, 8, 4),  256, 0, stream>>>(xnT, wbf, bq1, bk1, bv, bg, y1qk, yvg);
    t3_conv2     <<<dim3(128, 4, 4),  256, 0, stream>>>(y1qk, wbf, bq2, bk2, qkT, ksum);
    t3t_transpose<<<dim3(256, 4, 8),  256, 0, stream>>>(qkT, yvg, kC, vC);
    t4_kv        <<<dim3(2, 2, 128),  256, 0, stream>>>(kC, vC, kv);
    t4c_kvT      <<<dim3(256, 4),     256, 0, stream>>>(kv, kvT16);
    t5_z         <<<dim3(512, 4),     256, 0, stream>>>(qkT, ksum, z);
    t6_final     <<<dim3(256, 4),     256, 0, stream>>>(qkT, kvT16, yvg, z, wbf, bo, out);
}

// Round 7
// 409.163 us; speedup vs baseline: 1.0366x; 1.0366x over previous
//
#include <hip/hip_runtime.h>
#include <cstdint>
#include <cstddef>

// ---------------------------------------------------------------------------
// GAttn round 6: revert r5 dbuf regression (back to r4 single-buffer loops);
// NEW t23 = fused conv1+gelu+conv2+softplus for q/k path, y1 strip in LDS
// (64x264 padded) -> y1qk HBM round-trip eliminated, t3 kernel gone.
//   tw | t0 | t1 | t2(v,g only) | t23(q,k fused) | t3t | t4 | t4c | t5 | t6
// ---------------------------------------------------------------------------

#define DI __device__ __forceinline__

typedef __attribute__((ext_vector_type(8))) short bf16x8;
typedef __attribute__((ext_vector_type(4))) short bf16x4;
typedef __attribute__((ext_vector_type(4))) float f32x4;

static constexpr int Cc = 256;
static constexpr int NN = 16384;

DI float bf2f(short s){ unsigned int u = ((unsigned int)(unsigned short)s) << 16; float f; __builtin_memcpy(&f, &u, 4); return f; }
DI short f2bf(float f){ unsigned int u; __builtin_memcpy(&u, &f, 4); u += 0x7fffu + ((u >> 16) & 1u); return (short)(u >> 16); }

typedef __attribute__((address_space(1))) const unsigned int gu32;
typedef __attribute__((address_space(3))) unsigned int lu32;
DI void gload16(const short* g, short* l){
    __builtin_amdgcn_global_load_lds((gu32*)g, (lu32*)l, 16, 0, 0);
}

// gelu(x) = 0.5x(1+erf(x/sqrt2)); erf via A&S 7.1.26, |abs err| < 1.5e-7
DI float geluf(float x){
    float zz = x * 0.70710678118654752f;
    float az = fabsf(zz);
    float t  = __builtin_amdgcn_rcpf(fmaf(0.3275911f, az, 1.0f));
    float p  = fmaf(fmaf(fmaf(fmaf(1.061405429f, t, -1.453152027f), t,
                   1.421413741f), t, -0.284496736f), t, 0.254829592f) * t;
    float e  = __expf(-az * az);
    float er = copysignf(1.0f - p * e, zz);
    return 0.5f * x * (1.0f + er);
}
// softplus(x) = max(x,0) + log(1+exp(-|x|)); log arg in (1,2] -> v_log accurate
DI float softplusf(float x){
    float e = __expf(-fabsf(x));
    return fmaxf(x, 0.0f) + __logf(1.0f + e);
}

// ---------------- TW: one-shot weight fp32->bf16 ----------------
__global__ __launch_bounds__(256) void tw_conv(
    const float* __restrict__ W0, const float* __restrict__ W1,
    const float* __restrict__ W2, const float* __restrict__ W3,
    const float* __restrict__ W4, const float* __restrict__ W5,
    const float* __restrict__ W6, short* __restrict__ dst)
{
    const float* srcs[7] = {W0, W1, W2, W3, W4, W5, W6};
    const float* W = srcs[blockIdx.y];
    short* d = dst + (size_t)blockIdx.y * 65536;
    int i = blockIdx.x * 256 + threadIdx.x;
    float4 v = *(const float4*)(W + (size_t)i * 4);
    bf16x4 pk = { f2bf(v.x), f2bf(v.y), f2bf(v.z), f2bf(v.w) };
    *(bf16x4*)(d + (size_t)i * 4) = pk;
}

// ---------------- T0: instance-norm stats ----------------
__global__ __launch_bounds__(256) void t0_stats(const float* __restrict__ x,
                                                float* __restrict__ mu, float* __restrict__ rstd)
{
    int row = blockIdx.x;
    const float4* p = (const float4*)(x + (size_t)row * NN);
    float s = 0.f, ss = 0.f;
    for (int i = threadIdx.x; i < NN/4; i += 256){
        float4 v = p[i];
        s  += v.x + v.y + v.z + v.w;
        ss += v.x*v.x + v.y*v.y + v.z*v.z + v.w*v.w;
    }
    #pragma unroll
    for (int o = 32; o; o >>= 1){ s += __shfl_down(s, o); ss += __shfl_down(ss, o); }
    __shared__ float a0[4], a1[4];
    int w = threadIdx.x >> 6;
    if ((threadIdx.x & 63) == 0){ a0[w] = s; a1[w] = ss; }
    __syncthreads();
    if (threadIdx.x == 0){
        float S = a0[0]+a0[1]+a0[2]+a0[3], SS = a1[0]+a1[1]+a1[2]+a1[3];
        float m = S * (1.f/NN);
        float var = SS * (1.f/NN) - m*m;
        mu[row] = m;
        rstd[row] = rsqrtf(var + 1e-5f);
    }
}

// ---------------- T1: normalize + transpose -> xnT[b][n][c] ----------------
__global__ __launch_bounds__(256) void t1_xnT(const float* __restrict__ x,
                                              const float* __restrict__ mu, const float* __restrict__ rstd,
                                              short* __restrict__ xnT)
{
    int n0 = blockIdx.x * 64, c0 = blockIdx.y * 64, b = blockIdx.z;
    __shared__ __align__(16) short lds[64*72];
    int t = threadIdx.x;
    #pragma unroll
    for (int i = 0; i < 4; i++){
        int idx = i*256 + t;
        int c  = idx >> 4;
        int n4 = idx & 15;
        int cg = b*Cc + c0 + c;
        float4 v = *(const float4*)(x + (size_t)cg*NN + n0 + n4*4);
        float m = mu[cg], rs = rstd[cg];
        int key = (c ^ (c >> 3)) & 7;
        int blk = (n4 >> 1) ^ key;
        bf16x4 pk = { f2bf((v.x-m)*rs), f2bf((v.y-m)*rs), f2bf((v.z-m)*rs), f2bf((v.w-m)*rs) };
        *(bf16x4*)(&lds[c*72 + blk*8 + (n4&1)*4]) = pk;
    }
    __syncthreads();
    #pragma unroll
    for (int i = 0; i < 2; i++){
        int idx = i*256 + t;
        int n  = idx >> 3;
        int c8 = idx & 7;
        bf16x8 pk;
        #pragma unroll
        for (int j = 0; j < 8; j++){
            int c = c8*8 + j;
            int key = (c ^ (c >> 3)) & 7;
            pk[j] = lds[c*72 + (((n >> 3) ^ key))*8 + (n & 7)];
        }
        *(bf16x8*)(xnT + ((size_t)(b*NN + n0 + n))*Cc + c0 + c8*8) = pk;
    }
}

// ---------------- T2: conv1 (v,g branches only, gelu) ----------------
__global__ __launch_bounds__(256) void t2_conv1(const short* __restrict__ xnT,
    const short* __restrict__ wbf,
    const float* __restrict__ bv, const float* __restrict__ bg,
    short* __restrict__ yvg)
{
    int n0 = blockIdx.x * 128;
    int stile = blockIdx.y;             // 0..3 : branch v(0,1) g(2,3)
    int b = blockIdx.z;
    int branch = 2 + (stile >> 1);      // wbf index 2=Wv 3=Wg
    const short* wb = wbf + (size_t)branch * 65536;
    const float* bs = (stile >> 1) ? bg : bv;
    int s0b = (stile & 1) * 128;
    int dcol = stile * 128;             // v cols 0..255, g cols 256..511

    __shared__ __align__(16) short Al[128*32];
    __shared__ __align__(16) short Bl[128*32];
    int t = threadIdx.x, lane = t & 63, wid = t >> 6;
    int wm = (wid & 1) * 64, wn = (wid >> 1) * 64;
    int l15 = lane & 15, g = lane >> 4;
    int srow = wid*16 + (lane >> 2);        // + i*64
    int scol = (lane & 3) * 8;
    int sdst = wid*512 + lane*8;            // + i*2048

    f32x4 acc[4][4];
    #pragma unroll
    for (int i=0;i<4;i++)
        #pragma unroll
        for (int j=0;j<4;j++){ acc[i][j][0]=0.f; acc[i][j][1]=0.f; acc[i][j][2]=0.f; acc[i][j][3]=0.f; }

    const short* xb = xnT + (size_t)(b*NN + n0) * Cc;

    for (int k0 = 0; k0 < 256; k0 += 32){
        __syncthreads();
        #pragma unroll
        for (int i = 0; i < 2; i++){
            gload16(xb + (size_t)(i*64 + srow)*Cc + k0 + scol, &Al[i*2048 + sdst]);
            gload16(wb + (size_t)(s0b + i*64 + srow)*Cc + k0 + scol, &Bl[i*2048 + sdst]);
        }
        __syncthreads();
        bf16x8 bfr[4];
        #pragma unroll
        for (int ni = 0; ni < 4; ni++) bfr[ni] = *(const bf16x8*)(&Bl[(wn + ni*16 + l15)*32 + g*8]);
        #pragma unroll
        for (int mi = 0; mi < 4; mi++){
            bf16x8 a = *(const bf16x8*)(&Al[(wm + mi*16 + l15)*32 + g*8]);
            #pragma unroll
            for (int ni = 0; ni < 4; ni++)
                acc[mi][ni] = __builtin_amdgcn_mfma_f32_16x16x32_bf16(a, bfr[ni], acc[mi][ni], 0, 0, 0);
        }
    }
    short* outb = yvg + (size_t)(b*NN + n0) * 512 + dcol;
    #pragma unroll
    for (int mi = 0; mi < 4; mi++)
        #pragma unroll
        for (int ni = 0; ni < 4; ni++){
            int coll = wn + ni*16 + l15;
            float bias = bs[s0b + coll];
            #pragma unroll
            for (int r = 0; r < 4; r++){
                int row = wm + mi*16 + g*4 + r;
                outb[(size_t)row*512 + coll] = f2bf(geluf(acc[mi][ni][r] + bias));
            }
        }
}

// ---------------- T23: fused conv1+gelu+conv2+softplus (q,k) ----------------
__global__ __launch_bounds__(256) void t23_fused(const short* __restrict__ xnT,
    const short* __restrict__ wbf,
    const float* __restrict__ bq1, const float* __restrict__ bk1,
    const float* __restrict__ bq2, const float* __restrict__ bk2,
    short* __restrict__ qkT, float* __restrict__ ksum)
{
    int n0 = blockIdx.x * 64;
    int branch = blockIdx.y;            // 0=q, 1=k
    int b = blockIdx.z;
    const short* w1 = wbf + (size_t)branch * 65536;        // Wq1 / Wk1
    const short* w2 = wbf + (size_t)(4 + branch) * 65536;  // Wq2 / Wk2
    const float* bs1 = branch ? bk1 : bq1;
    const float* bs2 = branch ? bk2 : bq2;

    __shared__ __align__(16) short Al[64*32];     //  4 KB  A strip (xnT / -)
    __shared__ __align__(16) short Bl[256*32];    // 16 KB  W1 / W2 K-tile
    __shared__ __align__(16) short Y1[64*264];    // 33 KB  gelu(conv1) strip
    int t = threadIdx.x, lane = t & 63, wid = t >> 6;
    int wn = wid * 64;
    int l15 = lane & 15, g = lane >> 4;
    int srowA = t >> 2, scolA = (t & 3) * 8, sdstA = t * 8;
    int srowB = wid*16 + (lane >> 2);         // + i*64
    int scolB = (lane & 3) * 8;
    int sdstB = wid*512 + lane*8;             // + i*2048

    const short* xb = xnT + (size_t)(b*NN + n0) * Cc;

    f32x4 acc[4][4];
    #pragma unroll
    for (int i=0;i<4;i++)
        #pragma unroll
        for (int j=0;j<4;j++){ acc[i][j][0]=0.f; acc[i][j][1]=0.f; acc[i][j][2]=0.f; acc[i][j][3]=0.f; }

    // GEMM1: y1[n][s] = sum_c xnT[n][c] * W1[s][c]
    for (int k0 = 0; k0 < 256; k0 += 32){
        __syncthreads();
        gload16(xb + (size_t)srowA*Cc + k0 + scolA, &Al[sdstA]);
        #pragma unroll
        for (int i = 0; i < 4; i++)
            gload16(w1 + (size_t)(i*64 + srowB)*Cc + k0 + scolB, &Bl[i*2048 + sdstB]);
        __syncthreads();
        bf16x8 bfr[4];
        #pragma unroll
        for (int ni = 0; ni < 4; ni++) bfr[ni] = *(const bf16x8*)(&Bl[(wn + ni*16 + l15)*32 + g*8]);
        #pragma unroll
        for (int mi = 0; mi < 4; mi++){
            bf16x8 a = *(const bf16x8*)(&Al[(mi*16 + l15)*32 + g*8]);
            #pragma unroll
            for (int ni = 0; ni < 4; ni++)
                acc[mi][ni] = __builtin_amdgcn_mfma_f32_16x16x32_bf16(a, bfr[ni], acc[mi][ni], 0, 0, 0);
        }
    }
    // epilogue1: gelu -> Y1 strip (row = n-local, col = s)
    #pragma unroll
    for (int mi = 0; mi < 4; mi++)
        #pragma unroll
        for (int ni = 0; ni < 4; ni++){
            int coll = wn + ni*16 + l15;
            float bias = bs1[coll];
            #pragma unroll
            for (int r = 0; r < 4; r++){
                int row = mi*16 + g*4 + r;
                Y1[row*264 + coll] = f2bf(geluf(acc[mi][ni][r] + bias));
            }
        }

    // GEMM2: q/k[n][o] = sum_s y1[n][s] * W2[o][s]
    f32x4 acc2[4][4];
    #pragma unroll
    for (int i=0;i<4;i++)
        #pragma unroll
        for (int j=0;j<4;j++){ acc2[i][j][0]=0.f; acc2[i][j][1]=0.f; acc2[i][j][2]=0.f; acc2[i][j][3]=0.f; }

    for (int k0 = 0; k0 < 256; k0 += 32){
        __syncthreads();     // guards Bl overwrite; also publishes Y1 on first iter
        #pragma unroll
        for (int i = 0; i < 4; i++)
            gload16(w2 + (size_t)(i*64 + srowB)*Cc + k0 + scolB, &Bl[i*2048 + sdstB]);
        __syncthreads();
        bf16x8 bfr[4];
        #pragma unroll
        for (int ni = 0; ni < 4; ni++) bfr[ni] = *(const bf16x8*)(&Bl[(wn + ni*16 + l15)*32 + g*8]);
        #pragma unroll
        for (int mi = 0; mi < 4; mi++){
            bf16x8 a = *(const bf16x8*)(&Y1[(mi*16 + l15)*264 + k0 + g*8]);
            #pragma unroll
            for (int ni = 0; ni < 4; ni++)
                acc2[mi][ni] = __builtin_amdgcn_mfma_f32_16x16x32_bf16(a, bfr[ni], acc2[mi][ni], 0, 0, 0);
        }
    }
    // epilogue2: softplus -> qkT ; ksum atomics for k branch
    short* outb = qkT + (size_t)(b*NN + n0) * 512 + branch*256;
    float csum[4] = {0.f, 0.f, 0.f, 0.f};
    #pragma unroll
    for (int mi = 0; mi < 4; mi++)
        #pragma unroll
        for (int ni = 0; ni < 4; ni++){
            int coll = wn + ni*16 + l15;
            float bias = bs2[coll];
            #pragma unroll
            for (int r = 0; r < 4; r++){
                int row = mi*16 + g*4 + r;
                float val = softplusf(acc2[mi][ni][r] + bias);
                outb[(size_t)row*512 + coll] = f2bf(val);
                csum[ni] += val;
            }
        }
    if (branch == 1){
        #pragma unroll
        for (int ni = 0; ni < 4; ni++){
            float v = csum[ni];
            v += __shfl_xor(v, 16);
            v += __shfl_xor(v, 32);
            if (g == 0) atomicAdd(&ksum[b*Cc + wn + ni*16 + l15], v);
        }
    }
}

// ---------------- T3t: transpose k,v to c-major ----------------
__global__ __launch_bounds__(256) void t3t_transpose(const short* __restrict__ qkT, const short* __restrict__ yvg,
                                                     short* __restrict__ kC, short* __restrict__ vC)
{
    int n0 = blockIdx.x * 64;
    int c0 = blockIdx.y * 64;
    int b  = blockIdx.z >> 1;
    int which = blockIdx.z & 1;
    const short* src; short* dst;
    if (which == 0){ src = qkT + (size_t)(b*NN + n0)*512 + 256 + c0; dst = kC + (size_t)(b*Cc + c0)*NN + n0; }
    else           { src = yvg + (size_t)(b*NN + n0)*512 +   0 + c0; dst = vC + (size_t)(b*Cc + c0)*NN + n0; }
    __shared__ __align__(16) short lds[64*72];
    int t = threadIdx.x;
    #pragma unroll
    for (int i = 0; i < 2; i++){
        int idx = i*256 + t;
        int n = idx >> 3, c8 = idx & 7;
        bf16x8 v = *(const bf16x8*)(src + (size_t)n*512 + c8*8);
        int key = (n ^ (n >> 3)) & 7;
        *(bf16x8*)(&lds[n*72 + (c8 ^ key)*8]) = v;
    }
    __syncthreads();
    #pragma unroll
    for (int i = 0; i < 2; i++){
        int idx = i*256 + t;
        int c = idx >> 3, n8 = idx & 7;
        bf16x8 pk;
        #pragma unroll
        for (int j = 0; j < 8; j++){
            int n = n8*8 + j;
            int key = (n ^ (n >> 3)) & 7;
            pk[j] = lds[n*72 + (((c >> 3) ^ key))*8 + (c & 7)];
        }
        *(bf16x8*)(dst + (size_t)c*NN + n8*8) = pk;
    }
}

// ---------------- T4: kv GEMM (atomic K-split) ----------------
__global__ __launch_bounds__(256) void t4_kv(const short* __restrict__ kC, const short* __restrict__ vC,
                                             float* __restrict__ kv)
{
    int m0 = blockIdx.x * 128;          // c
    int d0 = blockIdx.y * 128;          // d
    int b  = blockIdx.z >> 5;
    int nb = (blockIdx.z & 31) * 512;

    __shared__ __align__(16) short Al[128*32];
    __shared__ __align__(16) short Bl[128*32];
    int t = threadIdx.x, lane = t & 63, wid = t >> 6;
    int wm = (wid & 1) * 64, wn = (wid >> 1) * 64;
    int l15 = lane & 15, g = lane >> 4;
    int srow = wid*16 + (lane >> 2);
    int scol = (lane & 3) * 8;
    int sdst = wid*512 + lane*8;

    f32x4 acc[4][4];
    #pragma unroll
    for (int i=0;i<4;i++)
        #pragma unroll
        for (int j=0;j<4;j++){ acc[i][j][0]=0.f; acc[i][j][1]=0.f; acc[i][j][2]=0.f; acc[i][j][3]=0.f; }

    const short* ka = kC + (size_t)(b*Cc + m0)*NN + nb;
    const short* vb = vC + (size_t)(b*Cc + d0)*NN + nb;

    for (int k0 = 0; k0 < 512; k0 += 32){
        __syncthreads();
        #pragma unroll
        for (int i = 0; i < 2; i++){
            gload16(ka + (size_t)(i*64 + srow)*NN + k0 + scol, &Al[i*2048 + sdst]);
            gload16(vb + (size_t)(i*64 + srow)*NN + k0 + scol, &Bl[i*2048 + sdst]);
        }
        __syncthreads();
        bf16x8 bfr[4];
        #pragma unroll
        for (int ni = 0; ni < 4; ni++) bfr[ni] = *(const bf16x8*)(&Bl[(wn + ni*16 + l15)*32 + g*8]);
        #pragma unroll
        for (int mi = 0; mi < 4; mi++){
            bf16x8 a = *(const bf16x8*)(&Al[(wm + mi*16 + l15)*32 + g*8]);
            #pragma unroll
            for (int ni = 0; ni < 4; ni++)
                acc[mi][ni] = __builtin_amdgcn_mfma_f32_16x16x32_bf16(a, bfr[ni], acc[mi][ni], 0, 0, 0);
        }
    }
    #pragma unroll
    for (int mi = 0; mi < 4; mi++)
        #pragma unroll
        for (int ni = 0; ni < 4; ni++){
            int coll = wn + ni*16 + l15;
            #pragma unroll
            for (int r = 0; r < 4; r++){
                int row = wm + mi*16 + g*4 + r;
                atomicAdd(&kv[((size_t)b*Cc + m0 + row)*Cc + d0 + coll], acc[mi][ni][r]);
            }
        }
}

// ---------------- T4c: kvT16[d][c] = bf16(kv[c][d]/16) ----------------
__global__ __launch_bounds__(256) void t4c_kvT(const float* __restrict__ kv, short* __restrict__ kvT16)
{
    int d = blockIdx.x, b = blockIdx.y, c = threadIdx.x;
    float v = kv[((size_t)b*Cc + c)*Cc + d] * 0.0625f;
    kvT16[((size_t)b*Cc + d)*Cc + c] = f2bf(v);
}

// ---------------- T5: z = 1/(q.ksum/16 + N) ----------------
__global__ __launch_bounds__(256) void t5_z(const short* __restrict__ qkT, const float* __restrict__ ksum,
                                            float* __restrict__ z)
{
    int b = blockIdx.y;
    int n0 = blockIdx.x * 32;
    __shared__ float ks[256];
    int t = threadIdx.x;
    ks[t] = ksum[b*Cc + t];
    __syncthreads();
    int row = n0 + (t >> 3), l8 = t & 7;
    const short* q = qkT + (size_t)(b*NN + row)*512;
    float acc = 0.f;
    #pragma unroll
    for (int i = 0; i < 4; i++){
        int c8 = i*8 + l8;
        bf16x8 v = *(const bf16x8*)(q + c8*8);
        #pragma unroll
        for (int j = 0; j < 8; j++) acc += bf2f(v[j]) * ks[c8*8 + j];
    }
    acc += __shfl_down(acc, 4, 8);
    acc += __shfl_down(acc, 2, 8);
    acc += __shfl_down(acc, 1, 8);
    if (l8 == 0) z[b*NN + row] = 1.0f / (acc * 0.0625f + 16384.0f);
}

// ---------------- T6: final fused (q.kvT16, gate, Wo conv) ----------------
__global__ __launch_bounds__(256) void t6_final(const short* __restrict__ qkT, const short* __restrict__ kvT16,
    const short* __restrict__ yvg, const float* __restrict__ z,
    const short* __restrict__ wbf, const float* __restrict__ bo, float* __restrict__ out)
{
    int n0 = blockIdx.x * 64, b = blockIdx.y;
    __shared__ __align__(16) short Aq[64*32];
    __shared__ __align__(16) short Bw[256*32];
    __shared__ __align__(16) short S[64*264];
    int t = threadIdx.x, lane = t & 63, wid = t >> 6;
    int l15 = lane & 15, g = lane >> 4;
    const short* wo_bf = wbf + (size_t)6 * 65536;
    int srow = wid*16 + (lane >> 2);        // + i*64
    int scol = (lane & 3) * 8;
    int sdst = wid*512 + lane*8;            // + i*2048

    f32x4 acc[4][4];
    #pragma unroll
    for (int i=0;i<4;i++)
        #pragma unroll
        for (int j=0;j<4;j++){ acc[i][j][0]=0.f; acc[i][j][1]=0.f; acc[i][j][2]=0.f; acc[i][j][3]=0.f; }

    const short* qb = qkT + (size_t)(b*NN + n0)*512;
    const short* kvb = kvT16 + (size_t)b*Cc*Cc;

    // GEMM-a: t[n][d] = sum_c q[n][c] * kvT16[d][c]
    for (int k0 = 0; k0 < 256; k0 += 32){
        __syncthreads();
        gload16(qb + (size_t)srow*512 + k0 + scol, &Aq[sdst]);   // 64 rows, 1 issue
        #pragma unroll
        for (int i = 0; i < 4; i++)
            gload16(kvb + (size_t)(i*64 + srow)*Cc + k0 + scol, &Bw[i*2048 + sdst]);
        __syncthreads();
        bf16x8 bfr[4];
        #pragma unroll
        for (int ni = 0; ni < 4; ni++) bfr[ni] = *(const bf16x8*)(&Bw[(wid*64 + ni*16 + l15)*32 + g*8]);
        #pragma unroll
        for (int mi = 0; mi < 4; mi++){
            bf16x8 a = *(const bf16x8*)(&Aq[(mi*16 + l15)*32 + g*8]);
            #pragma unroll
            for (int ni = 0; ni < 4; ni++)
                acc[mi][ni] = __builtin_amdgcn_mfma_f32_16x16x32_bf16(a, bfr[ni], acc[mi][ni], 0, 0, 0);
        }
    }
    // epilogue-a: s = (t + v) * z * g  -> S[n][d]
    #pragma unroll
    for (int mi = 0; mi < 4; mi++)
        #pragma unroll
        for (int r = 0; r < 4; r++){
            int nl = mi*16 + g*4 + r;
            float zv = z[b*NN + n0 + nl];
            const short* vrow = yvg + (size_t)(b*NN + n0 + nl)*512;
            #pragma unroll
            for (int ni = 0; ni < 4; ni++){
                int d = wid*64 + ni*16 + l15;
                float vv = bf2f(vrow[d]);
                float gg = bf2f(vrow[256 + d]);
                S[nl*264 + d] = f2bf((acc[mi][ni][r] + vv) * zv * gg);
            }
        }
    __syncthreads();

    // GEMM-b: out[o][n] = sum_d Wo[o][d] * S[n][d] + bo
    f32x4 acc2[4][4];
    #pragma unroll
    for (int i=0;i<4;i++)
        #pragma unroll
        for (int j=0;j<4;j++){ acc2[i][j][0]=0.f; acc2[i][j][1]=0.f; acc2[i][j][2]=0.f; acc2[i][j][3]=0.f; }

    for (int k0 = 0; k0 < 256; k0 += 32){
        __syncthreads();
        #pragma unroll
        for (int i = 0; i < 4; i++)
            gload16(wo_bf + (size_t)(i*64 + srow)*Cc + k0 + scol, &Bw[i*2048 + sdst]);
        __syncthreads();
        bf16x8 sfr[4];
        #pragma unroll
        for (int ni = 0; ni < 4; ni++) sfr[ni] = *(const bf16x8*)(&S[(ni*16 + l15)*264 + k0 + g*8]);
        #pragma unroll
        for (int mi = 0; mi < 4; mi++){
            bf16x8 a = *(const bf16x8*)(&Bw[(wid*64 + mi*16 + l15)*32 + g*8]);
            #pragma unroll
            for (int ni = 0; ni < 4; ni++)
                acc2[mi][ni] = __builtin_amdgcn_mfma_f32_16x16x32_bf16(a, sfr[ni], acc2[mi][ni], 0, 0, 0);
        }
    }
    #pragma unroll
    for (int mi = 0; mi < 4; mi++)
        #pragma unroll
        for (int ni = 0; ni < 4; ni++){
            int n = n0 + ni*16 + l15;
            #pragma unroll
            for (int r = 0; r < 4; r++){
                int o = wid*64 + mi*16 + g*4 + r;
                out[((size_t)b*Cc + o)*NN + n] = acc2[mi][ni][r] + bo[o];
            }
        }
}

// ---------------- host ----------------
extern "C" void kernel_launch(void* const* d_in, const int* in_sizes, int n_in,
                              void* d_out, int out_size, void* d_ws, size_t ws_size,
                              hipStream_t stream)
{
    (void)in_sizes; (void)n_in; (void)out_size; (void)ws_size;
    const float* x   = (const float*)d_in[0];
    const float* Wq1 = (const float*)d_in[1];
    const float* bq1 = (const float*)d_in[2];
    const float* Wq2 = (const float*)d_in[3];
    const float* bq2 = (const float*)d_in[4];
    const float* Wk1 = (const float*)d_in[5];
    const float* bk1 = (const float*)d_in[6];
    const float* Wk2 = (const float*)d_in[7];
    const float* bk2 = (const float*)d_in[8];
    const float* Wv  = (const float*)d_in[9];
    const float* bv  = (const float*)d_in[10];
    const float* Wg  = (const float*)d_in[11];
    const float* bg  = (const float*)d_in[12];
    const float* Wo  = (const float*)d_in[13];
    const float* bo  = (const float*)d_in[14];
    float* out = (float*)d_out;

    char* ws = (char*)d_ws;
    float* mu    = (float*)(ws + 0);                //   4 KB
    float* rstd  = (float*)(ws + 4096);             //   4 KB
    float* z     = (float*)(ws + 8192);             // 256 KB  (ends 270336)
    short* kvT16 = (short*)(ws + 270336);           // 512 KB  (ends 794624)
    short* wbf   = (short*)(ws + 794624);           // 896 KB  bf16 weights (ends 1712128)
    float* ksum  = (float*)(ws + 1712128);          //   4 KB  (memset 0)
    float* kv    = (float*)(ws + 1716224);          //   1 MB  (memset 0, ends 2764800)
    short* xnT   = (short*)(ws + 3145728);          //  32 MB  (ends 36700160)
    short* kC    = (short*)(ws + 36700160);         //  32 MB  (ends 70254592)
    short* vC    = (short*)(ws + 70254592);         //  32 MB  (ends 103809024)
    short* yvg   = (short*)(ws + 103809024);        //  64 MB  (ends 170917888)
    short* qkT   = (short*)(ws + 170917888);        //  64 MB  (ends 238026752)

    hipMemsetAsync(ws + 1712128, 0, 4096 + 1048576, stream);   // ksum + kv

    tw_conv      <<<dim3(64, 7),      256, 0, stream>>>(Wq1, Wk1, Wv, Wg, Wq2, Wk2, Wo, wbf);
    t0_stats     <<<dim3(1024),       256, 0, stream>>>(x, mu, rstd);
    t1_xnT       <<<dim3(256, 4, 4),  256, 0, stream>>>(x, mu, rstd, xnT);
    t2_conv1     <<<dim3(128, 4, 4),  256, 0, stream>>>(xnT, wbf, bv, bg, yvg);
    t23_fused    <<<dim3(256, 2, 4),  256, 0, stream>>>(xnT, wbf, bq1, bk1, bq2, bk2, qkT, ksum);
    t3t_transpose<<<dim3(256, 4, 8),  256, 0, stream>>>(qkT, yvg, kC, vC);
    t4_kv        <<<dim3(2, 2, 128),  256, 0, stream>>>(kC, vC, kv);
    t4c_kvT      <<<dim3(256, 4),     256, 0, stream>>>(kv, kvT16);
    t5_z         <<<dim3(512, 4),     256, 0, stream>>>(qkT, ksum, z);
    t6_final     <<<dim3(256, 4),     256, 0, stream>>>(qkT, kvT16, yvg, z, wbf, bo, out);
}